// Round 2
// baseline (41.807 us; speedup 1.0000x reference)
//
#include <hip/hip_runtime.h>

// out[b,n,m] = dot(m1[b,n,:], w[:512]) + dot(m2[b,m,:], w[512:]) + bias[0]
// B=8, N1=N2=2048, D=512, float32 everywhere.
// Memory-bound: 67 MB read + 134 MB write. Strategy:
//   K1: s2[b,m] = dot(m2 row, w2)           (reads 33.5 MB)
//   K2 (fused): per-wave: s1 = dot(m1 row, w1), then stream out row
//       out[b,n,:] = s1 + s2[b,:] + bias    (reads 33.5 MB, writes 134 MB)
// Nontemporal loads for streamed matrices, nontemporal stores for out
// (no reuse -> don't thrash L2; keep w/s2 resident).

#define DDIM 512
#define BB   8
#define NN   2048
#define ROWS (BB * NN)   // 16384 rows per matrix

typedef float f32x4 __attribute__((ext_vector_type(4)));

__device__ __forceinline__ float dot_row_wave(const f32x4* __restrict__ rp,
                                              const f32x4* __restrict__ wv,
                                              int lane) {
    f32x4 a0 = __builtin_nontemporal_load(rp + lane);
    f32x4 b0 = wv[lane];
    f32x4 a1 = __builtin_nontemporal_load(rp + lane + 64);
    f32x4 b1 = wv[lane + 64];
    float acc = a0.x * b0.x + a0.y * b0.y + a0.z * b0.z + a0.w * b0.w
              + a1.x * b1.x + a1.y * b1.y + a1.z * b1.z + a1.w * b1.w;
    // butterfly: all 64 lanes end with the full sum
    #pragma unroll
    for (int off = 1; off < 64; off <<= 1)
        acc += __shfl_xor(acc, off, 64);
    return acc;
}

// K1: one wave per m2 row -> s2[row]
__global__ __launch_bounds__(256) void dot2_kernel(const float* __restrict__ m2,
                                                   const float* __restrict__ w,
                                                   float* __restrict__ s2) {
    int wave = (int)((blockIdx.x * blockDim.x + threadIdx.x) >> 6);
    int lane = threadIdx.x & 63;
    const f32x4* rp = reinterpret_cast<const f32x4*>(m2 + (size_t)wave * DDIM);
    const f32x4* wv = reinterpret_cast<const f32x4*>(w + DDIM);
    float acc = dot_row_wave(rp, wv, lane);
    if (lane == 0) s2[wave] = acc;
}

// K2: one wave per m1 row. Compute s1 in-wave, then stream the 2048-float
// output row: out[row, m] = s1 + s2[b, m] + bias.
__global__ __launch_bounds__(256) void fused_kernel(const float* __restrict__ m1,
                                                    const float* __restrict__ w,
                                                    const float* __restrict__ s2,
                                                    const float* __restrict__ bias,
                                                    float* __restrict__ out) {
    int wave = (int)((blockIdx.x * blockDim.x + threadIdx.x) >> 6);  // row 0..16383
    int lane = threadIdx.x & 63;
    int b = wave >> 11;                                              // row / 2048

    const f32x4* rp = reinterpret_cast<const f32x4*>(m1 + (size_t)wave * DDIM);
    const f32x4* wv = reinterpret_cast<const f32x4*>(w);
    float s1 = dot_row_wave(rp, wv, lane);
    float v1 = s1 + bias[0];

    const f32x4* s2v = reinterpret_cast<const f32x4*>(s2 + (size_t)b * NN);
    f32x4* op = reinterpret_cast<f32x4*>(out + (size_t)wave * NN);

    #pragma unroll
    for (int k = 0; k < 8; ++k) {
        f32x4 v2 = s2v[lane + 64 * k];
        f32x4 r  = v2 + v1;
        __builtin_nontemporal_store(r, op + lane + 64 * k);
    }
}

extern "C" void kernel_launch(void* const* d_in, const int* in_sizes, int n_in,
                              void* d_out, int out_size, void* d_ws, size_t ws_size,
                              hipStream_t stream) {
    const float* m1   = (const float*)d_in[0];
    const float* m2   = (const float*)d_in[1];
    const float* w    = (const float*)d_in[2];
    const float* bias = (const float*)d_in[3];
    float* out = (float*)d_out;
    float* s2  = (float*)d_ws;   // 16384 floats

    // 16384 waves, 4 per 256-thread block
    dot2_kernel<<<ROWS / 4, 256, 0, stream>>>(m2, w, s2);
    fused_kernel<<<ROWS / 4, 256, 0, stream>>>(m1, w, s2, bias, out);
}

// Round 3
// 37.585 us; speedup vs baseline: 1.1123x; 1.1123x over previous
//
#include <hip/hip_runtime.h>

// out[b,n,m] = dot(m1[b,n,:], w[:512]) + dot(m2[b,m,:], w[512:]) + bias[0]
// B=8, N1=N2=2048, D=512, float32 everywhere.
// Memory-bound: 67 MB read + 134 MB write (floor ~29 us at 7 TB/s).
// Round-1 structure (proven 37.8us) with a higher-MLP dot kernel:
//   K1: s1/s2 dots, 4 rows per wave (8 float4 loads/lane in flight)
//   K2: pure-write broadcast add (s1/s2 are 64KB each -> L2-resident)

#define DDIM 512
#define BB   8
#define NN   2048
#define ROWS (BB * NN)          // 16384 rows per matrix
#define RPW  4                  // rows per wave in dot kernel

typedef float f32x4 __attribute__((ext_vector_type(4)));

// K1: each wave computes RPW consecutive rows of one matrix.
// Virtual rows [0,16384) -> m1 with w1; [16384,32768) -> m2 with w2.
// RPW divides 16384 so a group never straddles the two matrices.
__global__ __launch_bounds__(256) void dot_kernel(const float* __restrict__ m1,
                                                  const float* __restrict__ m2,
                                                  const float* __restrict__ w,
                                                  float* __restrict__ s) {
    int wave  = (int)((blockIdx.x * blockDim.x + threadIdx.x) >> 6);
    int lane  = threadIdx.x & 63;
    int vrow0 = wave * RPW;                 // virtual row base, [0, 32768)

    const float* src;
    const float* wp;
    int row0;
    if (vrow0 < ROWS) { src = m1; wp = w;        row0 = vrow0; }
    else              { src = m2; wp = w + DDIM; row0 = vrow0 - ROWS; }

    const f32x4* wv = reinterpret_cast<const f32x4*>(wp);
    f32x4 w0 = wv[lane];
    f32x4 w1 = wv[lane + 64];

    // Issue all row loads up front for MLP.
    f32x4 a0[RPW], a1[RPW];
    #pragma unroll
    for (int r = 0; r < RPW; ++r) {
        const f32x4* rp = reinterpret_cast<const f32x4*>(src + (size_t)(row0 + r) * DDIM);
        a0[r] = rp[lane];
        a1[r] = rp[lane + 64];
    }

    float acc[RPW];
    #pragma unroll
    for (int r = 0; r < RPW; ++r) {
        acc[r] = a0[r].x * w0.x + a0[r].y * w0.y + a0[r].z * w0.z + a0[r].w * w0.w
               + a1[r].x * w1.x + a1[r].y * w1.y + a1[r].z * w1.z + a1[r].w * w1.w;
    }

    // 4 independent butterfly chains (ILP across rows).
    #pragma unroll
    for (int r = 0; r < RPW; ++r) {
        #pragma unroll
        for (int off = 1; off < 64; off <<= 1)
            acc[r] += __shfl_xor(acc[r], off, 64);
    }

    if (lane == 0) {
        #pragma unroll
        for (int r = 0; r < RPW; ++r)
            s[vrow0 + r] = acc[r];
    }
}

// K2: out[b,n,m] = s1[b,n] + s2[b,m] + bias. Pure write stream; s1/s2/bias
// all L2-resident (64KB each). Plain float4 stores, linear grid-stride.
__global__ __launch_bounds__(256) void add_kernel(const float* __restrict__ s1,
                                                  const float* __restrict__ s2,
                                                  const float* __restrict__ bias,
                                                  f32x4* __restrict__ out) {
    const size_t total4 = (size_t)BB * NN * (NN / 4);   // 8.39M float4s
    const float bval = bias[0];
    const f32x4* s2v = reinterpret_cast<const f32x4*>(s2);

    for (size_t i = (size_t)blockIdx.x * blockDim.x + threadIdx.x;
         i < total4;
         i += (size_t)gridDim.x * blockDim.x) {
        int m4    = (int)(i & (NN / 4 - 1));        // 0..511
        size_t t  = i >> 9;                          // /512
        int n     = (int)(t & (NN - 1));             // 0..2047
        int b     = (int)(t >> 11);                  // 0..7

        float v1 = s1[b * NN + n] + bval;
        f32x4 v2 = s2v[b * (NN / 4) + m4];
        out[i] = v2 + v1;
    }
}

extern "C" void kernel_launch(void* const* d_in, const int* in_sizes, int n_in,
                              void* d_out, int out_size, void* d_ws, size_t ws_size,
                              hipStream_t stream) {
    const float* m1   = (const float*)d_in[0];
    const float* m2   = (const float*)d_in[1];
    const float* w    = (const float*)d_in[2];
    const float* bias = (const float*)d_in[3];
    float* out = (float*)d_out;

    float* s  = (float*)d_ws;          // s1: [0,16384), s2: [16384,32768)
    float* s1 = s;
    float* s2 = s + ROWS;

    // 32768 rows / 4 rows-per-wave = 8192 waves = 2048 blocks of 256
    dot_kernel<<<(2 * ROWS) / (RPW * 4), 256, 0, stream>>>(m1, m2, w, s);

    // 8.39M float4s; 2048 blocks x 256 threads, grid-stride (16 iters each)
    add_kernel<<<2048, 256, 0, stream>>>(s1, s2, bias, (f32x4*)out);
}

// Round 4
// 36.518 us; speedup vs baseline: 1.1448x; 1.0292x over previous
//
#include <hip/hip_runtime.h>

// out[b,n,m] = dot(m1[b,n,:], w[:512]) + dot(m2[b,m,:], w[512:]) + bias[0]
// B=8, N1=N2=2048, D=512, float32. Memory-bound: 67 MB read + 134 MB write.
// K1 (unchanged from R3): per-wave dots, 4 rows/wave.
// K2 (new): tiled broadcast-add. Each wave owns an 8n x 512m tile:
//   s2 chunk -> 2 f32x4 regs (once), s1 -> 8 uniform scalars (once),
//   then 16 pure 1KB streaming stores. Kills the per-store L2 read + index
//   math that throttled the flat grid-stride version (~5.2 TB/s vs fill's 7.1).

#define DDIM 512
#define BB   8
#define NN   2048
#define ROWS (BB * NN)          // 16384 rows per matrix
#define RPW  4                  // rows per wave in dot kernel
#define WROWS  8                // rows per wave in add kernel
#define MCHUNK 512              // m-columns per wave in add kernel

typedef float f32x4 __attribute__((ext_vector_type(4)));

// K1: each wave computes RPW consecutive rows of one matrix.
// Virtual rows [0,16384) -> m1 with w1; [16384,32768) -> m2 with w2.
__global__ __launch_bounds__(256) void dot_kernel(const float* __restrict__ m1,
                                                  const float* __restrict__ m2,
                                                  const float* __restrict__ w,
                                                  float* __restrict__ s) {
    int wave  = (int)((blockIdx.x * blockDim.x + threadIdx.x) >> 6);
    int lane  = threadIdx.x & 63;
    int vrow0 = wave * RPW;                 // virtual row base, [0, 32768)

    const float* src;
    const float* wp;
    int row0;
    if (vrow0 < ROWS) { src = m1; wp = w;        row0 = vrow0; }
    else              { src = m2; wp = w + DDIM; row0 = vrow0 - ROWS; }

    const f32x4* wv = reinterpret_cast<const f32x4*>(wp);
    f32x4 w0 = wv[lane];
    f32x4 w1 = wv[lane + 64];

    f32x4 a0[RPW], a1[RPW];
    #pragma unroll
    for (int r = 0; r < RPW; ++r) {
        const f32x4* rp = reinterpret_cast<const f32x4*>(src + (size_t)(row0 + r) * DDIM);
        a0[r] = rp[lane];
        a1[r] = rp[lane + 64];
    }

    float acc[RPW];
    #pragma unroll
    for (int r = 0; r < RPW; ++r) {
        acc[r] = a0[r].x * w0.x + a0[r].y * w0.y + a0[r].z * w0.z + a0[r].w * w0.w
               + a1[r].x * w1.x + a1[r].y * w1.y + a1[r].z * w1.z + a1[r].w * w1.w;
    }

    #pragma unroll
    for (int r = 0; r < RPW; ++r) {
        #pragma unroll
        for (int off = 1; off < 64; off <<= 1)
            acc[r] += __shfl_xor(acc[r], off, 64);
    }

    if (lane == 0) {
        #pragma unroll
        for (int r = 0; r < RPW; ++r)
            s[vrow0 + r] = acc[r];
    }
}

// K2: each wave handles an 8-row x 512-col output tile.
// tile id: m_chunk (0..3) fastest, then n-group (0..255), then b (0..7).
__global__ __launch_bounds__(256) void add_kernel(const float* __restrict__ s1,
                                                  const float* __restrict__ s2,
                                                  const float* __restrict__ bias,
                                                  float* __restrict__ out) {
    int wave = (int)((blockIdx.x * blockDim.x + threadIdx.x) >> 6);  // 0..8191
    int lane = threadIdx.x & 63;
    int m_chunk = wave & (NN / MCHUNK - 1);     // 0..3
    int bn      = wave >> 2;                    // 0..2047
    int n0      = (bn & (NN / WROWS - 1)) * WROWS;  // 0..2040
    int b       = bn >> 8;                      // 0..7

    const float bval = bias[0];

    // s2 chunk: 512 floats -> 2 f32x4 per lane, loaded once.
    const f32x4* s2v = reinterpret_cast<const f32x4*>(s2 + (size_t)b * NN + m_chunk * MCHUNK);
    f32x4 v2a = s2v[lane];
    f32x4 v2b = s2v[lane + 64];

    const float* s1p = s1 + (size_t)b * NN + n0;   // 8 wave-uniform scalars
    float* op = out + ((size_t)(b * NN + n0)) * NN + m_chunk * MCHUNK;

    #pragma unroll
    for (int r = 0; r < WROWS; ++r) {
        float v1 = s1p[r] + bval;
        f32x4* orow = reinterpret_cast<f32x4*>(op + (size_t)r * NN);
        orow[lane]      = v2a + v1;
        orow[lane + 64] = v2b + v1;
    }
}

extern "C" void kernel_launch(void* const* d_in, const int* in_sizes, int n_in,
                              void* d_out, int out_size, void* d_ws, size_t ws_size,
                              hipStream_t stream) {
    const float* m1   = (const float*)d_in[0];
    const float* m2   = (const float*)d_in[1];
    const float* w    = (const float*)d_in[2];
    const float* bias = (const float*)d_in[3];
    float* out = (float*)d_out;

    float* s  = (float*)d_ws;          // s1: [0,16384), s2: [16384,32768)
    float* s1 = s;
    float* s2 = s + ROWS;

    // 32768 rows / 4 rows-per-wave = 8192 waves = 2048 blocks of 256
    dot_kernel<<<(2 * ROWS) / (RPW * 4), 256, 0, stream>>>(m1, m2, w, s);

    // 8192 tiles (8 b x 256 n-groups x 4 m-chunks), 4 waves/block -> 2048 blocks
    add_kernel<<<2048, 256, 0, stream>>>(s1, s2, bias, out);
}

// Round 5
// 36.127 us; speedup vs baseline: 1.1572x; 1.0108x over previous
//
#include <hip/hip_runtime.h>

// out[b,n,m] = dot(m1[b,n,:], w[:512]) + dot(m2[b,m,:], w[512:]) + bias[0]
// B=8, N1=N2=2048, D=512, float32. Memory-bound: 67 MB read + 134 MB write.
//
// K1: s2[b,m] = dot(m2 row, w2). 4 rows/wave. 33.5 MB read-only pass.
// K2 (fused): each wave owns 4 FULL-WIDTH output rows (4 x 2048 floats).
//   - reads its 4 m1 rows (8 KB, exactly once grid-wide: no redundancy)
//   - preloads s2[b] (2048 floats) into 8 f32x4 regs, reused for all 4 rows
//   - 4 ILP butterfly reductions -> s1 values
//   - 32 KB plain streaming stores (f32x4, 1 KB contiguous per wave-step)
//   m1 reads overlap the write stream instead of being a serial phase.
//   (R2's fused regression used NT stores + 1 row/wave; both removed here.)

#define DDIM 512
#define BB   8
#define NN   2048
#define ROWS (BB * NN)          // 16384 rows per matrix
#define RPW  4                  // rows per wave (both kernels)

typedef float f32x4 __attribute__((ext_vector_type(4)));

// K1: s2 only. Each wave: 4 consecutive m2 rows.
__global__ __launch_bounds__(256) void dot2_kernel(const float* __restrict__ m2,
                                                   const float* __restrict__ w,
                                                   float* __restrict__ s2) {
    int wave = (int)((blockIdx.x * blockDim.x + threadIdx.x) >> 6);
    int lane = threadIdx.x & 63;
    int row0 = wave * RPW;

    const f32x4* wv = reinterpret_cast<const f32x4*>(w + DDIM);
    f32x4 w0 = wv[lane];
    f32x4 w1 = wv[lane + 64];

    f32x4 a0[RPW], a1[RPW];
    #pragma unroll
    for (int r = 0; r < RPW; ++r) {
        const f32x4* rp = reinterpret_cast<const f32x4*>(m2 + (size_t)(row0 + r) * DDIM);
        a0[r] = rp[lane];
        a1[r] = rp[lane + 64];
    }

    float acc[RPW];
    #pragma unroll
    for (int r = 0; r < RPW; ++r)
        acc[r] = a0[r].x * w0.x + a0[r].y * w0.y + a0[r].z * w0.z + a0[r].w * w0.w
               + a1[r].x * w1.x + a1[r].y * w1.y + a1[r].z * w1.z + a1[r].w * w1.w;

    #pragma unroll
    for (int r = 0; r < RPW; ++r) {
        #pragma unroll
        for (int off = 1; off < 64; off <<= 1)
            acc[r] += __shfl_xor(acc[r], off, 64);
    }

    if (lane == 0) {
        #pragma unroll
        for (int r = 0; r < RPW; ++r)
            s2[row0 + r] = acc[r];
    }
}

// K2: fused. Each wave: 4 full-width output rows.
__global__ __launch_bounds__(256) void fused_kernel(const float* __restrict__ m1,
                                                    const float* __restrict__ w,
                                                    const float* __restrict__ s2,
                                                    const float* __restrict__ bias,
                                                    float* __restrict__ out) {
    int wave = (int)((blockIdx.x * blockDim.x + threadIdx.x) >> 6);  // 0..4095
    int lane = threadIdx.x & 63;
    int row0 = wave * RPW;               // global n-row in [0,16384)
    int b    = row0 >> 11;               // row0 / 2048

    const f32x4* wv = reinterpret_cast<const f32x4*>(w);
    f32x4 w0 = wv[lane];
    f32x4 w1 = wv[lane + 64];

    // m1 rows (issue all loads up front)
    f32x4 a0[RPW], a1[RPW];
    #pragma unroll
    for (int r = 0; r < RPW; ++r) {
        const f32x4* rp = reinterpret_cast<const f32x4*>(m1 + (size_t)(row0 + r) * DDIM);
        a0[r] = rp[lane];
        a1[r] = rp[lane + 64];
    }

    // s2[b,:] -> 8 f32x4 per lane (32 VGPR), reused for all 4 rows (L2-hot)
    const f32x4* s2v = reinterpret_cast<const f32x4*>(s2 + (size_t)b * NN);
    f32x4 v2[NN / 4 / 64];               // 8
    #pragma unroll
    for (int k = 0; k < NN / 4 / 64; ++k)
        v2[k] = s2v[lane + 64 * k];

    float acc[RPW];
    #pragma unroll
    for (int r = 0; r < RPW; ++r)
        acc[r] = a0[r].x * w0.x + a0[r].y * w0.y + a0[r].z * w0.z + a0[r].w * w0.w
               + a1[r].x * w1.x + a1[r].y * w1.y + a1[r].z * w1.z + a1[r].w * w1.w;

    #pragma unroll
    for (int r = 0; r < RPW; ++r) {
        #pragma unroll
        for (int off = 1; off < 64; off <<= 1)
            acc[r] += __shfl_xor(acc[r], off, 64);
    }

    const float bval = bias[0];
    #pragma unroll
    for (int r = 0; r < RPW; ++r) {
        float v1 = acc[r] + bval;
        f32x4* orow = reinterpret_cast<f32x4*>(out + (size_t)(row0 + r) * NN);
        #pragma unroll
        for (int k = 0; k < NN / 4 / 64; ++k)
            orow[lane + 64 * k] = v2[k] + v1;
    }
}

extern "C" void kernel_launch(void* const* d_in, const int* in_sizes, int n_in,
                              void* d_out, int out_size, void* d_ws, size_t ws_size,
                              hipStream_t stream) {
    const float* m1   = (const float*)d_in[0];
    const float* m2   = (const float*)d_in[1];
    const float* w    = (const float*)d_in[2];
    const float* bias = (const float*)d_in[3];
    float* out = (float*)d_out;
    float* s2  = (float*)d_ws;   // 16384 floats

    // K1: 16384 rows / 4 per wave = 4096 waves = 1024 blocks
    dot2_kernel<<<ROWS / (RPW * 4), 256, 0, stream>>>(m2, w, s2);

    // K2: 16384 rows / 4 per wave = 4096 waves = 1024 blocks
    fused_kernel<<<ROWS / (RPW * 4), 256, 0, stream>>>(m1, w, s2, bias, out);
}